// Round 1
// baseline (392.733 us; speedup 1.0000x reference)
//
#include <hip/hip_runtime.h>
#include <stdint.h>

#define E_       8
#define D_       1024
#define DFFN_    2048
#define T_       8192
#define TK_      16384
#define CAP_     16896
#define NBR_     64        // TK_/256 rank blocks
#define MAXTILES_ 160

// workspace layout (bytes)
#define WS_SEL      0u          // TK_*4
#define WS_COUNTS   0x10000u    // 8*4
#define WS_CUMP     0x10100u    // 9*4
#define WS_TOTALS   0x10200u    // [0]=total_padded [1]=nTiles
#define WS_BLKCNT   0x10300u    // NBR_*8*4
#define WS_BLKOFF   0x10B00u    // NBR_*8*4
#define WS_TILES    0x11300u    // MAXTILES_*4
#define WS_ROWSRC   0x12000u    // CAP_*4
#define WS_XPAD     0x23000u    // CAP_*1024*2 = 34603008
#define WS_W1T      (0x23000u + 34603008u)  // 16384*1024*2

typedef __bf16 bf16x8 __attribute__((ext_vector_type(8)));
typedef float  f32x4  __attribute__((ext_vector_type(4)));

__device__ __forceinline__ unsigned short f2bf(float f) {
  union { float f; uint32_t u; } v; v.f = f;
  return (unsigned short)((v.u + 0x7fffu + ((v.u >> 16) & 1u)) >> 16);
}

// ---------------- 1. router: top-2 expert ids + counts ----------------
__global__ __launch_bounds__(256) void k_router(const float* __restrict__ x,
                                                const float* __restrict__ wr,
                                                int* __restrict__ sel,
                                                int* __restrict__ counts) {
  __shared__ float lwr[E_ * D_];
  for (int i = threadIdx.x; i < E_ * D_ / 4; i += 256)
    ((float4*)lwr)[i] = ((const float4*)wr)[i];
  __syncthreads();
  int wave = threadIdx.x >> 6, lane = threadIdx.x & 63;
  int t = blockIdx.x * 4 + wave;
  double acc[E_];
#pragma unroll
  for (int e = 0; e < E_; ++e) acc[e] = 0.0;
  const float4* xr = (const float4*)(x + (size_t)t * D_);
#pragma unroll
  for (int j = 0; j < 4; ++j) {
    float4 v = xr[j * 64 + lane];
    int dbase = j * 256 + lane * 4;
#pragma unroll
    for (int e = 0; e < E_; ++e) {
      const float* w = lwr + e * D_ + dbase;
      acc[e] += (double)v.x * w[0] + (double)v.y * w[1] +
                (double)v.z * w[2] + (double)v.w * w[3];
    }
  }
#pragma unroll
  for (int e = 0; e < E_; ++e) {
    double v = acc[e];
    for (int off = 32; off >= 1; off >>= 1) v += __shfl_xor(v, off, 64);
    acc[e] = v;
  }
  if (lane == 0) {
    int e1 = 0;
    for (int e = 1; e < E_; ++e) if (acc[e] > acc[e1]) e1 = e;
    int e2 = (e1 == 0) ? 1 : 0;
    for (int e = 0; e < E_; ++e) if (e != e1 && acc[e] > acc[e2]) e2 = e;
    sel[2 * t]     = e1;
    sel[2 * t + 1] = e2;
    atomicAdd(&counts[e1], 1);
    atomicAdd(&counts[e2], 1);
  }
}

// ---------------- 2. per-block expert histograms ----------------
__global__ __launch_bounds__(256) void k_blkcnt(const int* __restrict__ sel,
                                                int* __restrict__ blkCnt) {
  __shared__ int cnt[E_];
  if (threadIdx.x < E_) cnt[threadIdx.x] = 0;
  __syncthreads();
  atomicAdd(&cnt[sel[blockIdx.x * 256 + threadIdx.x]], 1);
  __syncthreads();
  if (threadIdx.x < E_) blkCnt[blockIdx.x * E_ + threadIdx.x] = cnt[threadIdx.x];
}

// ---------------- 3. tiny scans + tile table (1 block) ----------------
__global__ void k_scan(const int* __restrict__ counts, const int* __restrict__ blkCnt,
                       int* __restrict__ cum_p, int* __restrict__ totals,
                       int* __restrict__ blkOff, int* __restrict__ tiles) {
  int tid = threadIdx.x;
  if (tid < E_) {
    int run = 0;
    for (int b = 0; b < NBR_; ++b) {
      blkOff[b * E_ + tid] = run;
      run += blkCnt[b * E_ + tid];
    }
  }
  if (tid == 0) {
    int cp = 0, nt = 0;
    cum_p[0] = 0;
    for (int e = 0; e < E_; ++e) {
      int gs = (counts[e] + 63) / 64 * 64;
      int r = 0;
      while (r < gs) {
        int m = (gs - r >= 128) ? 128 : 64;
        tiles[nt++] = (cp + r) | (e << 20) | ((m == 128) ? (1 << 28) : 0);
        r += m;
      }
      cp += gs;
      cum_p[e + 1] = cp;
    }
    totals[0] = cp;
    totals[1] = nt;
  }
}

// ---------------- 4. stable rank -> row_src ----------------
__global__ __launch_bounds__(256) void k_rowsrc(const int* __restrict__ sel,
                                                const int* __restrict__ cum_p,
                                                const int* __restrict__ blkOff,
                                                int* __restrict__ row_src) {
  __shared__ int se[256];
  int i = blockIdx.x * 256 + threadIdx.x;
  int e = sel[i];
  se[threadIdx.x] = e;
  __syncthreads();
  int r = 0;
  for (int j = 0; j < threadIdx.x; ++j) r += (se[j] == e);
  row_src[cum_p[e] + blkOff[blockIdx.x * E_ + e] + r] = i >> 1;
}

// ---------------- 5. scatter x -> padded bf16 rows ----------------
__global__ __launch_bounds__(256) void k_scatter(const float* __restrict__ x,
                                                 const int* __restrict__ row_src,
                                                 unsigned short* __restrict__ xp) {
  int row = blockIdx.x;
  int src = row_src[row];
  ushort4 o;
  if (src >= 0) {
    float4 v = ((const float4*)(x + (size_t)src * D_))[threadIdx.x];
    o.x = f2bf(v.x); o.y = f2bf(v.y); o.z = f2bf(v.z); o.w = f2bf(v.w);
  } else {
    o.x = 0; o.y = 0; o.z = 0; o.w = 0;
  }
  ((ushort4*)(xp + (size_t)row * D_))[threadIdx.x] = o;
}

// ---------------- 6. w1 [d][16384] f32 -> w1t [n][1024] bf16 ----------------
__global__ __launch_bounds__(256) void k_w1conv(const float* __restrict__ w1,
                                                unsigned short* __restrict__ w1t) {
  __shared__ unsigned short lds[64][258];
  int n0 = blockIdx.x * 256, d0 = blockIdx.y * 64;
  int tid = threadIdx.x;
  int rIn = tid >> 6, c4 = tid & 63;
#pragma unroll
  for (int p = 0; p < 16; ++p) {
    int row = p * 4 + rIn;
    float4 v = *(const float4*)(w1 + (size_t)(d0 + row) * 16384 + n0 + c4 * 4);
    lds[row][c4 * 4 + 0] = f2bf(v.x);
    lds[row][c4 * 4 + 1] = f2bf(v.y);
    lds[row][c4 * 4 + 2] = f2bf(v.z);
    lds[row][c4 * 4 + 3] = f2bf(v.w);
  }
  __syncthreads();
  int d2 = (tid & 15) * 4, nn = tid >> 4;
#pragma unroll
  for (int q = 0; q < 16; ++q) {
    int n = q * 16 + nn;
    ushort4 o;
    o.x = lds[d2 + 0][n]; o.y = lds[d2 + 1][n];
    o.z = lds[d2 + 2][n]; o.w = lds[d2 + 3][n];
    *(ushort4*)(w1t + (size_t)(n0 + n) * 1024 + d0 + d2) = o;
  }
}

// ---------------- 7. grouped GEMM (m97-style 128x128, BK=64) ----------------
#define BM_ 128
#define BN_ 128
#define BK_ 64

__global__ __launch_bounds__(256) void k_gemm(const unsigned short* __restrict__ xp,
                                              const unsigned short* __restrict__ w1t,
                                              const int* __restrict__ tiles,
                                              const int* __restrict__ totals,
                                              float* __restrict__ out) {
  if ((int)blockIdx.x >= totals[1]) return;
  int info = tiles[blockIdx.x];
  int rowBase = info & 0xFFFFF;
  int e = (info >> 20) & 0xFF;
  int mLimit = ((info >> 28) & 1) ? 128 : 64;
  int nTile = blockIdx.y;

  __shared__ unsigned short As[BM_ * BK_];
  __shared__ unsigned short Bs[BN_ * BK_];

  int tid = threadIdx.x, wave = tid >> 6, lane = tid & 63;
  int wr = wave >> 1, wc = wave & 1;

  f32x4 acc[4][4];
#pragma unroll
  for (int i = 0; i < 4; ++i)
#pragma unroll
    for (int j = 0; j < 4; ++j) acc[i][j] = (f32x4){0.f, 0.f, 0.f, 0.f};

  const unsigned short* Ag = xp + (size_t)rowBase * D_;
  const unsigned short* Bg = w1t + ((size_t)e * DFFN_ + (size_t)nTile * BN_) * D_;
  int srow = (lane >> 3);          // 0..7
  int scol = (lane & 7) * 8;       // bf16 elems, 16B per lane

  for (int k0 = 0; k0 < D_; k0 += BK_) {
#pragma unroll
    for (int c = 0; c < 4; ++c) {
      int rbase = wave * 32 + c * 8;
      __builtin_amdgcn_global_load_lds(
          (const __attribute__((address_space(1))) void*)(Ag + (size_t)(rbase + srow) * D_ + k0 + scol),
          (__attribute__((address_space(3))) void*)(As + rbase * BK_), 16, 0, 0);
      __builtin_amdgcn_global_load_lds(
          (const __attribute__((address_space(1))) void*)(Bg + (size_t)(rbase + srow) * D_ + k0 + scol),
          (__attribute__((address_space(3))) void*)(Bs + rbase * BK_), 16, 0, 0);
    }
    __syncthreads();
#pragma unroll
    for (int ks = 0; ks < BK_; ks += 32) {
      bf16x8 a[4], b[4];
#pragma unroll
      for (int i = 0; i < 4; ++i)
        a[i] = *(const bf16x8*)(As + (wr * 64 + i * 16 + (lane & 15)) * BK_ + ks + (lane >> 4) * 8);
#pragma unroll
      for (int i = 0; i < 4; ++i)
        b[i] = *(const bf16x8*)(Bs + (wc * 64 + i * 16 + (lane & 15)) * BK_ + ks + (lane >> 4) * 8);
#pragma unroll
      for (int i = 0; i < 4; ++i)
#pragma unroll
        for (int j = 0; j < 4; ++j)
          acc[i][j] = __builtin_amdgcn_mfma_f32_16x16x32_bf16(a[i], b[j], acc[i][j], 0, 0, 0);
    }
    __syncthreads();
  }

  // epilogue: C/D layout col=lane&15, row=(lane>>4)*4+reg
#pragma unroll
  for (int i = 0; i < 4; ++i) {
    int mBase = wr * 64 + i * 16;
    if (mBase >= mLimit) continue;
    int r0 = mBase + (lane >> 4) * 4;
#pragma unroll
    for (int j = 0; j < 4; ++j) {
      int n = nTile * BN_ + wc * 64 + j * 16 + (lane & 15);
      f32x4 v = acc[i][j];
#pragma unroll
      for (int q = 0; q < 4; ++q)
        out[(size_t)(rowBase + r0 + q) * DFFN_ + n] = v[q];
    }
  }
}

// ---------------- 8. zero tail rows >= total_padded ----------------
__global__ __launch_bounds__(256) void k_ztail(const int* __restrict__ totals,
                                               float* __restrict__ out) {
  int row = TK_ + blockIdx.x;          // 16384 .. 16895
  if (row < totals[0]) return;
  float4 z = {0.f, 0.f, 0.f, 0.f};
  float4* o = (float4*)(out + (size_t)row * DFFN_);
  o[threadIdx.x] = z;
  o[threadIdx.x + 256] = z;
}

extern "C" void kernel_launch(void* const* d_in, const int* in_sizes, int n_in,
                              void* d_out, int out_size, void* d_ws, size_t ws_size,
                              hipStream_t stream) {
  const float* x  = (const float*)d_in[0];
  const float* wr = (const float*)d_in[1];
  const float* w1 = (const float*)d_in[2];
  float* out = (float*)d_out;
  char* ws = (char*)d_ws;

  int* sel     = (int*)(ws + WS_SEL);
  int* counts  = (int*)(ws + WS_COUNTS);
  int* cum_p   = (int*)(ws + WS_CUMP);
  int* totals  = (int*)(ws + WS_TOTALS);
  int* blkCnt  = (int*)(ws + WS_BLKCNT);
  int* blkOff  = (int*)(ws + WS_BLKOFF);
  int* tiles   = (int*)(ws + WS_TILES);
  int* row_src = (int*)(ws + WS_ROWSRC);
  unsigned short* xp  = (unsigned short*)(ws + WS_XPAD);
  unsigned short* w1t = (unsigned short*)(ws + WS_W1T);

  hipMemsetAsync(counts, 0, E_ * sizeof(int), stream);
  hipMemsetAsync(row_src, 0xFF, CAP_ * sizeof(int), stream);

  k_w1conv<<<dim3(64, 16), 256, 0, stream>>>(w1, w1t);
  k_router<<<T_ / 4, 256, 0, stream>>>(x, wr, sel, counts);
  k_blkcnt<<<NBR_, 256, 0, stream>>>(sel, blkCnt);
  k_scan<<<1, 64, 0, stream>>>(counts, blkCnt, cum_p, totals, blkOff, tiles);
  k_rowsrc<<<NBR_, 256, 0, stream>>>(sel, cum_p, blkOff, row_src);
  k_scatter<<<CAP_, 256, 0, stream>>>(x, row_src, xp);
  k_gemm<<<dim3(MAXTILES_, DFFN_ / BN_), 256, 0, stream>>>(xp, w1t, tiles, totals, out);
  k_ztail<<<512, 256, 0, stream>>>(totals, out);
}

// Round 2
// 223.131 us; speedup vs baseline: 1.7601x; 1.7601x over previous
//
#include <hip/hip_runtime.h>
#include <stdint.h>

#define E_       8
#define D_       1024
#define DFFN_    2048
#define T_       8192
#define TK_      16384
#define CAP_     16896
#define NBR_     64        // TK_/256 rank blocks
#define MAXTILES_ 160

// workspace layout (bytes)
#define WS_SEL      0u          // TK_*4
#define WS_COUNTS   0x10000u    // 8*4
#define WS_CUMP     0x10100u    // 9*4
#define WS_TOTALS   0x10200u    // [0]=total_padded [1]=nTiles
#define WS_BLKCNT   0x10300u    // NBR_*8*4
#define WS_BLKOFF   0x10B00u    // NBR_*8*4
#define WS_TILES    0x11300u    // MAXTILES_*4
#define WS_ROWSRC   0x12000u    // CAP_*4
#define WS_XPAD     0x23000u    // CAP_*1024*2 = 34603008
#define WS_W1T      (0x23000u + 34603008u)  // 16384*1024*2

typedef __bf16 bf16x8 __attribute__((ext_vector_type(8)));
typedef float  f32x4  __attribute__((ext_vector_type(4)));

__device__ __forceinline__ unsigned short f2bf(float f) {
  union { float f; uint32_t u; } v; v.f = f;
  return (unsigned short)((v.u + 0x7fffu + ((v.u >> 16) & 1u)) >> 16);
}

// ---------------- 1. router: top-2 expert ids (NO global atomics) ----------------
__global__ __launch_bounds__(256) void k_router(const float* __restrict__ x,
                                                const float* __restrict__ wr,
                                                int* __restrict__ sel) {
  __shared__ float lwr[E_ * D_];
  for (int i = threadIdx.x; i < E_ * D_ / 4; i += 256)
    ((float4*)lwr)[i] = ((const float4*)wr)[i];
  __syncthreads();
  int wave = threadIdx.x >> 6, lane = threadIdx.x & 63;

  for (int tk = 0; tk < 4; ++tk) {
    int t = blockIdx.x * 16 + wave * 4 + tk;
    double acc[E_];
#pragma unroll
    for (int e = 0; e < E_; ++e) acc[e] = 0.0;
    const float4* xr = (const float4*)(x + (size_t)t * D_);
#pragma unroll
    for (int j = 0; j < 4; ++j) {
      float4 v = xr[j * 64 + lane];
      int dbase = j * 256 + lane * 4;
#pragma unroll
      for (int e = 0; e < E_; ++e) {
        float4 w = *(const float4*)(lwr + e * D_ + dbase);
        acc[e] += (double)v.x * w.x + (double)v.y * w.y +
                  (double)v.z * w.z + (double)v.w * w.w;
      }
    }
    // butterfly within 8-lane groups (all 8 experts)
#pragma unroll
    for (int e = 0; e < E_; ++e) {
      acc[e] += __shfl_xor(acc[e], 1, 64);
      acc[e] += __shfl_xor(acc[e], 2, 64);
      acc[e] += __shfl_xor(acc[e], 4, 64);
    }
    // lane picks expert (lane&7) via static select tree
    double s01 = (lane & 1) ? acc[1] : acc[0];
    double s23 = (lane & 1) ? acc[3] : acc[2];
    double s45 = (lane & 1) ? acc[5] : acc[4];
    double s67 = (lane & 1) ? acc[7] : acc[6];
    double t0 = (lane & 2) ? s23 : s01;
    double t1 = (lane & 2) ? s67 : s45;
    double u  = (lane & 4) ? t1 : t0;
    // reduce across the 8 groups
    u += __shfl_xor(u, 8, 64);
    u += __shfl_xor(u, 16, 64);
    u += __shfl_xor(u, 32, 64);
    // broadcast the 8 logits to all lanes
    double lg[E_];
#pragma unroll
    for (int e = 0; e < E_; ++e) lg[e] = __shfl(u, e, 64);
    int e1 = 0; double b1 = lg[0];
#pragma unroll
    for (int e = 1; e < E_; ++e) if (lg[e] > b1) { b1 = lg[e]; e1 = e; }
    int e2 = (e1 == 0) ? 1 : 0; double b2 = lg[e2];
#pragma unroll
    for (int e = 0; e < E_; ++e) if (e != e1 && lg[e] > b2) { b2 = lg[e]; e2 = e; }
    if (lane == 0) {
      sel[2 * t]     = e1;
      sel[2 * t + 1] = e2;
    }
  }
}

// ---------------- 2. per-block expert histograms ----------------
__global__ __launch_bounds__(256) void k_blkcnt(const int* __restrict__ sel,
                                                int* __restrict__ blkCnt) {
  __shared__ int cnt[E_];
  if (threadIdx.x < E_) cnt[threadIdx.x] = 0;
  __syncthreads();
  atomicAdd(&cnt[sel[blockIdx.x * 256 + threadIdx.x]], 1);
  __syncthreads();
  if (threadIdx.x < E_) blkCnt[blockIdx.x * E_ + threadIdx.x] = cnt[threadIdx.x];
}

// ---------------- 3. tiny scans + tile table (1 block) ----------------
__global__ void k_scan(const int* __restrict__ blkCnt,
                       int* __restrict__ counts,
                       int* __restrict__ cum_p, int* __restrict__ totals,
                       int* __restrict__ blkOff, int* __restrict__ tiles) {
  int tid = threadIdx.x;
  if (tid < E_) {
    int run = 0;
    for (int b = 0; b < NBR_; ++b) {
      blkOff[b * E_ + tid] = run;
      run += blkCnt[b * E_ + tid];
    }
    counts[tid] = run;     // total tokens for expert tid (replaces router atomics)
  }
  __syncthreads();
  if (tid == 0) {
    int cp = 0, nt = 0;
    cum_p[0] = 0;
    for (int e = 0; e < E_; ++e) {
      int gs = (counts[e] + 63) / 64 * 64;
      int r = 0;
      while (r < gs) {
        int m = (gs - r >= 128) ? 128 : 64;
        tiles[nt++] = (cp + r) | (e << 20) | ((m == 128) ? (1 << 28) : 0);
        r += m;
      }
      cp += gs;
      cum_p[e + 1] = cp;
    }
    totals[0] = cp;
    totals[1] = nt;
  }
}

// ---------------- 4. stable rank -> row_src ----------------
__global__ __launch_bounds__(256) void k_rowsrc(const int* __restrict__ sel,
                                                const int* __restrict__ cum_p,
                                                const int* __restrict__ blkOff,
                                                int* __restrict__ row_src) {
  __shared__ int se[256];
  int i = blockIdx.x * 256 + threadIdx.x;
  int e = sel[i];
  se[threadIdx.x] = e;
  __syncthreads();
  int r = 0;
  for (int j = 0; j < threadIdx.x; ++j) r += (se[j] == e);
  row_src[cum_p[e] + blkOff[blockIdx.x * E_ + e] + r] = i >> 1;
}

// ---------------- 5. scatter x -> padded bf16 rows ----------------
__global__ __launch_bounds__(256) void k_scatter(const float* __restrict__ x,
                                                 const int* __restrict__ row_src,
                                                 unsigned short* __restrict__ xp) {
  int row = blockIdx.x;
  int src = row_src[row];
  ushort4 o;
  if (src >= 0) {
    float4 v = ((const float4*)(x + (size_t)src * D_))[threadIdx.x];
    o.x = f2bf(v.x); o.y = f2bf(v.y); o.z = f2bf(v.z); o.w = f2bf(v.w);
  } else {
    o.x = 0; o.y = 0; o.z = 0; o.w = 0;
  }
  ((ushort4*)(xp + (size_t)row * D_))[threadIdx.x] = o;
}

// ---------------- 6. w1 [d][16384] f32 -> w1t [n][1024] bf16 ----------------
__global__ __launch_bounds__(256) void k_w1conv(const float* __restrict__ w1,
                                                unsigned short* __restrict__ w1t) {
  __shared__ unsigned short lds[64][258];
  int n0 = blockIdx.x * 256, d0 = blockIdx.y * 64;
  int tid = threadIdx.x;
  int rIn = tid >> 6, c4 = tid & 63;
#pragma unroll
  for (int p = 0; p < 16; ++p) {
    int row = p * 4 + rIn;
    float4 v = *(const float4*)(w1 + (size_t)(d0 + row) * 16384 + n0 + c4 * 4);
    lds[row][c4 * 4 + 0] = f2bf(v.x);
    lds[row][c4 * 4 + 1] = f2bf(v.y);
    lds[row][c4 * 4 + 2] = f2bf(v.z);
    lds[row][c4 * 4 + 3] = f2bf(v.w);
  }
  __syncthreads();
  int d2 = (tid & 15) * 4, nn = tid >> 4;
#pragma unroll
  for (int q = 0; q < 16; ++q) {
    int n = q * 16 + nn;
    ushort4 o;
    o.x = lds[d2 + 0][n]; o.y = lds[d2 + 1][n];
    o.z = lds[d2 + 2][n]; o.w = lds[d2 + 3][n];
    *(ushort4*)(w1t + (size_t)(n0 + n) * 1024 + d0 + d2) = o;
  }
}

// ---------------- 7. grouped GEMM (m97-style 128x128, BK=64) ----------------
#define BM_ 128
#define BN_ 128
#define BK_ 64

__global__ __launch_bounds__(256) void k_gemm(const unsigned short* __restrict__ xp,
                                              const unsigned short* __restrict__ w1t,
                                              const int* __restrict__ tiles,
                                              const int* __restrict__ totals,
                                              float* __restrict__ out) {
  if ((int)blockIdx.x >= totals[1]) return;
  int info = tiles[blockIdx.x];
  int rowBase = info & 0xFFFFF;
  int e = (info >> 20) & 0xFF;
  int mLimit = ((info >> 28) & 1) ? 128 : 64;
  int nTile = blockIdx.y;

  __shared__ unsigned short As[BM_ * BK_];
  __shared__ unsigned short Bs[BN_ * BK_];

  int tid = threadIdx.x, wave = tid >> 6, lane = tid & 63;
  int wr = wave >> 1, wc = wave & 1;

  f32x4 acc[4][4];
#pragma unroll
  for (int i = 0; i < 4; ++i)
#pragma unroll
    for (int j = 0; j < 4; ++j) acc[i][j] = (f32x4){0.f, 0.f, 0.f, 0.f};

  const unsigned short* Ag = xp + (size_t)rowBase * D_;
  const unsigned short* Bg = w1t + ((size_t)e * DFFN_ + (size_t)nTile * BN_) * D_;
  int srow = (lane >> 3);          // 0..7
  int scol = (lane & 7) * 8;       // bf16 elems, 16B per lane

  for (int k0 = 0; k0 < D_; k0 += BK_) {
#pragma unroll
    for (int c = 0; c < 4; ++c) {
      int rbase = wave * 32 + c * 8;
      __builtin_amdgcn_global_load_lds(
          (const __attribute__((address_space(1))) void*)(Ag + (size_t)(rbase + srow) * D_ + k0 + scol),
          (__attribute__((address_space(3))) void*)(As + rbase * BK_), 16, 0, 0);
      __builtin_amdgcn_global_load_lds(
          (const __attribute__((address_space(1))) void*)(Bg + (size_t)(rbase + srow) * D_ + k0 + scol),
          (__attribute__((address_space(3))) void*)(Bs + rbase * BK_), 16, 0, 0);
    }
    __syncthreads();
#pragma unroll
    for (int ks = 0; ks < BK_; ks += 32) {
      bf16x8 a[4], b[4];
#pragma unroll
      for (int i = 0; i < 4; ++i)
        a[i] = *(const bf16x8*)(As + (wr * 64 + i * 16 + (lane & 15)) * BK_ + ks + (lane >> 4) * 8);
#pragma unroll
      for (int i = 0; i < 4; ++i)
        b[i] = *(const bf16x8*)(Bs + (wc * 64 + i * 16 + (lane & 15)) * BK_ + ks + (lane >> 4) * 8);
#pragma unroll
      for (int i = 0; i < 4; ++i)
#pragma unroll
        for (int j = 0; j < 4; ++j)
          acc[i][j] = __builtin_amdgcn_mfma_f32_16x16x32_bf16(a[i], b[j], acc[i][j], 0, 0, 0);
    }
    __syncthreads();
  }

  // epilogue: C/D layout col=lane&15, row=(lane>>4)*4+reg
#pragma unroll
  for (int i = 0; i < 4; ++i) {
    int mBase = wr * 64 + i * 16;
    if (mBase >= mLimit) continue;
    int r0 = mBase + (lane >> 4) * 4;
#pragma unroll
    for (int j = 0; j < 4; ++j) {
      int n = nTile * BN_ + wc * 64 + j * 16 + (lane & 15);
      f32x4 v = acc[i][j];
#pragma unroll
      for (int q = 0; q < 4; ++q)
        out[(size_t)(rowBase + r0 + q) * DFFN_ + n] = v[q];
    }
  }
}

// ---------------- 8. zero tail rows >= total_padded ----------------
__global__ __launch_bounds__(256) void k_ztail(const int* __restrict__ totals,
                                               float* __restrict__ out) {
  int row = TK_ + blockIdx.x;          // 16384 .. 16895
  if (row < totals[0]) return;
  float4 z = {0.f, 0.f, 0.f, 0.f};
  float4* o = (float4*)(out + (size_t)row * DFFN_);
  o[threadIdx.x] = z;
  o[threadIdx.x + 256] = z;
}

extern "C" void kernel_launch(void* const* d_in, const int* in_sizes, int n_in,
                              void* d_out, int out_size, void* d_ws, size_t ws_size,
                              hipStream_t stream) {
  const float* x  = (const float*)d_in[0];
  const float* wr = (const float*)d_in[1];
  const float* w1 = (const float*)d_in[2];
  float* out = (float*)d_out;
  char* ws = (char*)d_ws;

  int* sel     = (int*)(ws + WS_SEL);
  int* counts  = (int*)(ws + WS_COUNTS);
  int* cum_p   = (int*)(ws + WS_CUMP);
  int* totals  = (int*)(ws + WS_TOTALS);
  int* blkCnt  = (int*)(ws + WS_BLKCNT);
  int* blkOff  = (int*)(ws + WS_BLKOFF);
  int* tiles   = (int*)(ws + WS_TILES);
  int* row_src = (int*)(ws + WS_ROWSRC);
  unsigned short* xp  = (unsigned short*)(ws + WS_XPAD);
  unsigned short* w1t = (unsigned short*)(ws + WS_W1T);

  hipMemsetAsync(row_src, 0xFF, CAP_ * sizeof(int), stream);

  k_w1conv<<<dim3(64, 16), 256, 0, stream>>>(w1, w1t);
  k_router<<<T_ / 16, 256, 0, stream>>>(x, wr, sel);
  k_blkcnt<<<NBR_, 256, 0, stream>>>(sel, blkCnt);
  k_scan<<<1, 64, 0, stream>>>(blkCnt, counts, cum_p, totals, blkOff, tiles);
  k_rowsrc<<<NBR_, 256, 0, stream>>>(sel, cum_p, blkOff, row_src);
  k_scatter<<<CAP_, 256, 0, stream>>>(x, row_src, xp);
  k_gemm<<<dim3(MAXTILES_, DFFN_ / BN_), 256, 0, stream>>>(xp, w1t, tiles, totals, out);
  k_ztail<<<512, 256, 0, stream>>>(totals, out);
}

// Round 3
// 203.767 us; speedup vs baseline: 1.9274x; 1.0950x over previous
//
#include <hip/hip_runtime.h>
#include <stdint.h>

#define E_       8
#define D_       1024
#define DFFN_    2048
#define T_       8192
#define TK_      16384
#define CAP_     16896
#define NBR_     64        // TK_/256 rank blocks
#define MAXT_    96        // max 256-row tiles

// workspace layout (bytes)
#define WS_SEL      0u          // TK_*4
#define WS_COUNTS   0x10000u    // 8*4
#define WS_CUMP     0x10100u    // 9*4
#define WS_TOTALS   0x10200u    // [0]=total_padded [1]=nTiles
#define WS_BLKCNT   0x10300u    // NBR_*8*4
#define WS_BLKOFF   0x10B00u    // NBR_*8*4
#define WS_TILES    0x11300u    // MAXT_*4
#define WS_ROWSRC   0x12000u    // CAP_*4
#define WS_XPAD     0x23000u    // CAP_*1024*2 = 34603008
#define WS_W1T      (0x23000u + 34603008u)  // 16384*1024*2

typedef __bf16 bf16x8 __attribute__((ext_vector_type(8)));
typedef float  f32x4  __attribute__((ext_vector_type(4)));

#define VMCNT(N) asm volatile("s_waitcnt vmcnt(" #N ")" ::: "memory")
#define BAR()    asm volatile("s_barrier" ::: "memory")

__device__ __forceinline__ unsigned short f2bf(float f) {
  union { float f; uint32_t u; } v; v.f = f;
  return (unsigned short)((v.u + 0x7fffu + ((v.u >> 16) & 1u)) >> 16);
}

// ---------------- 1. router: top-2 expert ids (no global atomics) ----------------
__global__ __launch_bounds__(256) void k_router(const float* __restrict__ x,
                                                const float* __restrict__ wr,
                                                int* __restrict__ sel) {
  __shared__ float lwr[E_ * D_];
  for (int i = threadIdx.x; i < E_ * D_ / 4; i += 256)
    ((float4*)lwr)[i] = ((const float4*)wr)[i];
  __syncthreads();
  int wave = threadIdx.x >> 6, lane = threadIdx.x & 63;

  for (int tk = 0; tk < 4; ++tk) {
    int t = blockIdx.x * 16 + wave * 4 + tk;
    double acc[E_];
#pragma unroll
    for (int e = 0; e < E_; ++e) acc[e] = 0.0;
    const float4* xr = (const float4*)(x + (size_t)t * D_);
#pragma unroll
    for (int j = 0; j < 4; ++j) {
      float4 v = xr[j * 64 + lane];
      int dbase = j * 256 + lane * 4;
#pragma unroll
      for (int e = 0; e < E_; ++e) {
        float4 w = *(const float4*)(lwr + e * D_ + dbase);
        acc[e] += (double)v.x * w.x + (double)v.y * w.y +
                  (double)v.z * w.z + (double)v.w * w.w;
      }
    }
#pragma unroll
    for (int e = 0; e < E_; ++e) {
      acc[e] += __shfl_xor(acc[e], 1, 64);
      acc[e] += __shfl_xor(acc[e], 2, 64);
      acc[e] += __shfl_xor(acc[e], 4, 64);
    }
    double s01 = (lane & 1) ? acc[1] : acc[0];
    double s23 = (lane & 1) ? acc[3] : acc[2];
    double s45 = (lane & 1) ? acc[5] : acc[4];
    double s67 = (lane & 1) ? acc[7] : acc[6];
    double t0 = (lane & 2) ? s23 : s01;
    double t1 = (lane & 2) ? s67 : s45;
    double u  = (lane & 4) ? t1 : t0;
    u += __shfl_xor(u, 8, 64);
    u += __shfl_xor(u, 16, 64);
    u += __shfl_xor(u, 32, 64);
    double lg[E_];
#pragma unroll
    for (int e = 0; e < E_; ++e) lg[e] = __shfl(u, e, 64);
    int e1 = 0; double b1 = lg[0];
#pragma unroll
    for (int e = 1; e < E_; ++e) if (lg[e] > b1) { b1 = lg[e]; e1 = e; }
    int e2 = (e1 == 0) ? 1 : 0; double b2 = lg[e2];
#pragma unroll
    for (int e = 0; e < E_; ++e) if (e != e1 && lg[e] > b2) { b2 = lg[e]; e2 = e; }
    if (lane == 0) {
      sel[2 * t]     = e1;
      sel[2 * t + 1] = e2;
    }
  }
}

// ---------------- 2. per-block expert histograms ----------------
__global__ __launch_bounds__(256) void k_blkcnt(const int* __restrict__ sel,
                                                int* __restrict__ blkCnt) {
  __shared__ int cnt[E_];
  if (threadIdx.x < E_) cnt[threadIdx.x] = 0;
  __syncthreads();
  atomicAdd(&cnt[sel[blockIdx.x * 256 + threadIdx.x]], 1);
  __syncthreads();
  if (threadIdx.x < E_) blkCnt[blockIdx.x * E_ + threadIdx.x] = cnt[threadIdx.x];
}

// ---------------- 3. tiny scans + 256-row tile table (1 block) ----------------
__global__ void k_scan(const int* __restrict__ blkCnt,
                       int* __restrict__ counts,
                       int* __restrict__ cum_p, int* __restrict__ totals,
                       int* __restrict__ blkOff, int* __restrict__ tiles) {
  int tid = threadIdx.x;
  if (tid < E_) {
    int run = 0;
    for (int b = 0; b < NBR_; ++b) {
      blkOff[b * E_ + tid] = run;
      run += blkCnt[b * E_ + tid];
    }
    counts[tid] = run;
  }
  __syncthreads();
  if (tid == 0) {
    int cp = 0, nt = 0;
    cum_p[0] = 0;
    for (int e = 0; e < E_; ++e) {
      int gs = (counts[e] + 63) / 64 * 64;
      int r = 0;
      while (r < gs) {
        int m = (gs - r >= 256) ? 256 : (gs - r);   // 64,128,192,256
        tiles[nt++] = (cp + r) | (e << 20) | (((m >> 6) - 1) << 28);
        r += m;
      }
      cp += gs;
      cum_p[e + 1] = cp;
    }
    totals[0] = cp;
    totals[1] = nt;
  }
}

// ---------------- 4. stable rank -> row_src ----------------
__global__ __launch_bounds__(256) void k_rowsrc(const int* __restrict__ sel,
                                                const int* __restrict__ cum_p,
                                                const int* __restrict__ blkOff,
                                                int* __restrict__ row_src) {
  __shared__ int se[256];
  int i = blockIdx.x * 256 + threadIdx.x;
  int e = sel[i];
  se[threadIdx.x] = e;
  __syncthreads();
  int r = 0;
  for (int j = 0; j < threadIdx.x; ++j) r += (se[j] == e);
  row_src[cum_p[e] + blkOff[blockIdx.x * E_ + e] + r] = i >> 1;
}

// ---------------- 5. scatter x -> padded bf16 rows ----------------
__global__ __launch_bounds__(256) void k_scatter(const float* __restrict__ x,
                                                 const int* __restrict__ row_src,
                                                 unsigned short* __restrict__ xp) {
  int row = blockIdx.x;
  int src = row_src[row];
  ushort4 o;
  if (src >= 0) {
    float4 v = ((const float4*)(x + (size_t)src * D_))[threadIdx.x];
    o.x = f2bf(v.x); o.y = f2bf(v.y); o.z = f2bf(v.z); o.w = f2bf(v.w);
  } else {
    o.x = 0; o.y = 0; o.z = 0; o.w = 0;
  }
  ((ushort4*)(xp + (size_t)row * D_))[threadIdx.x] = o;
}

// ---------------- 6. w1 [d][16384] f32 -> w1t [n][1024] bf16 ----------------
__global__ __launch_bounds__(256) void k_w1conv(const float* __restrict__ w1,
                                                unsigned short* __restrict__ w1t) {
  __shared__ unsigned short lds[64][258];
  int n0 = blockIdx.x * 256, d0 = blockIdx.y * 64;
  int tid = threadIdx.x;
  int rIn = tid >> 6, c4 = tid & 63;
#pragma unroll
  for (int p = 0; p < 16; ++p) {
    int row = p * 4 + rIn;
    float4 v = *(const float4*)(w1 + (size_t)(d0 + row) * 16384 + n0 + c4 * 4);
    lds[row][c4 * 4 + 0] = f2bf(v.x);
    lds[row][c4 * 4 + 1] = f2bf(v.y);
    lds[row][c4 * 4 + 2] = f2bf(v.z);
    lds[row][c4 * 4 + 3] = f2bf(v.w);
  }
  __syncthreads();
  int d2 = (tid & 15) * 4, nn = tid >> 4;
#pragma unroll
  for (int q = 0; q < 16; ++q) {
    int n = q * 16 + nn;
    ushort4 o;
    o.x = lds[d2 + 0][n]; o.y = lds[d2 + 1][n];
    o.z = lds[d2 + 2][n]; o.w = lds[d2 + 3][n];
    *(ushort4*)(w1t + (size_t)(n0 + n) * 1024 + d0 + d2) = o;
  }
}

// ---------------- 7. grouped GEMM: 256x256 tile, BK=64, 8-phase pipeline ----------------
// LDS layout per buffer: [256 rows][64 bf16], swizzled: byte_in_row ^= (row&7)<<4.
// Staged via global_load_lds (linear dest) from inverse-swizzled global source.

__device__ __forceinline__ void stage64(const unsigned short* gbase, // points at (row0, k0)
                                        unsigned short* ldsq,        // region row0 elem ptr
                                        int tid) {
  int rr = tid >> 3;                                   // 0..63 row within 64-row region
  int co = ((tid & 7) ^ (rr & 7)) << 3;                // elem offset (inverse swizzle)
  const unsigned short* src = gbase + (size_t)rr * 1024 + co;
  unsigned short* dst = ldsq + ((tid >> 6) << 9);      // wave*512 elems; HW adds lane*16B
  __builtin_amdgcn_global_load_lds(
      (const __attribute__((address_space(1))) void*)src,
      (__attribute__((address_space(3))) void*)dst, 16, 0, 0);
}

#define PHASE_READS(MH, NH)                                                     \
  {                                                                             \
    const unsigned short* Ab_ = Acur + (wr * 128 + (MH) * 64 + lane15) * 64;    \
    const unsigned short* Bb_ = Bcur + (wc * 64 + (NH) * 32 + lane15) * 64;     \
    _Pragma("unroll") for (int ks = 0; ks < 2; ++ks) {                          \
      int co = (((ks * 64 + g16) ^ swz) >> 1);                                  \
      _Pragma("unroll") for (int mi = 0; mi < 4; ++mi)                          \
        a[ks][mi] = *(const bf16x8*)(Ab_ + mi * 1024 + co);                     \
      _Pragma("unroll") for (int ni = 0; ni < 2; ++ni)                          \
        b[ks][ni] = *(const bf16x8*)(Bb_ + ni * 1024 + co);                     \
    }                                                                           \
  }

#define PHASE_MFMA(MH, NH)                                                      \
  __builtin_amdgcn_s_setprio(1);                                                \
  _Pragma("unroll") for (int ks = 0; ks < 2; ++ks)                              \
    _Pragma("unroll") for (int mi = 0; mi < 4; ++mi)                            \
      _Pragma("unroll") for (int ni = 0; ni < 2; ++ni)                          \
        acc[(MH) * 4 + mi][(NH) * 2 + ni] = __builtin_amdgcn_mfma_f32_16x16x32_bf16( \
            a[ks][mi], b[ks][ni], acc[(MH) * 4 + mi][(NH) * 2 + ni], 0, 0, 0);  \
  __builtin_amdgcn_s_setprio(0);

__global__ __launch_bounds__(512) void k_gemm(const unsigned short* __restrict__ xp,
                                              const unsigned short* __restrict__ w1t,
                                              const int* __restrict__ tiles,
                                              const int* __restrict__ totals,
                                              float* __restrict__ out) {
  // T1: bijective XCD chunking (768 = 8*96); 8 N-tiles of one M-tile share an XCD.
  int P = blockIdx.y * MAXT_ + blockIdx.x;
  int L = (P & 7) * MAXT_ + (P >> 3);
  int mtile = L >> 3, ny = L & 7;
  if (mtile >= totals[1]) return;

  int info = tiles[mtile];
  int rowBase = info & 0xFFFFF;
  int e = (info >> 20) & 0xFF;
  int mLimit = (((info >> 28) & 3) + 1) << 6;

  __shared__ unsigned short As[2 * 256 * 64];
  __shared__ unsigned short Bs[2 * 256 * 64];

  int tid = threadIdx.x, wave = tid >> 6, lane = tid & 63;
  int lane15 = lane & 15;
  int g16 = (lane >> 4) * 16;          // byte offset of k-group
  int swz = (lane15 & 7) << 4;         // read-side swizzle (bytes)
  int wr = wave >> 2, wc = wave & 3;

  const unsigned short* Ag = xp + (size_t)rowBase * D_;
  const unsigned short* Bg = w1t + ((size_t)e * DFFN_ + (size_t)ny * 256) * D_;

  f32x4 acc[8][4];
#pragma unroll
  for (int i = 0; i < 8; ++i)
#pragma unroll
    for (int j = 0; j < 4; ++j) acc[i][j] = (f32x4){0.f, 0.f, 0.f, 0.f};

  // prologue: stage K-tile 0 into buf0 (order: B q0..q3, A q0,q2, A q1,q3)
  stage64(Bg + 0 * 64 * 1024, Bs + 0 * 4096, tid);
  stage64(Bg + 1 * 64 * 1024, Bs + 1 * 4096, tid);
  stage64(Bg + 2 * 64 * 1024, Bs + 2 * 4096, tid);
  stage64(Bg + 3 * 64 * 1024, Bs + 3 * 4096, tid);
  stage64(Ag + 0 * 64 * 1024, As + 0 * 4096, tid);
  stage64(Ag + 2 * 64 * 1024, As + 2 * 4096, tid);
  stage64(Ag + 1 * 64 * 1024, As + 1 * 4096, tid);
  stage64(Ag + 3 * 64 * 1024, As + 3 * 4096, tid);
  VMCNT(2);
  BAR();

  for (int t = 0; t < 16; ++t) {
    const unsigned short* Acur = As + (t & 1) * 16384;
    const unsigned short* Bcur = Bs + (t & 1) * 16384;
    unsigned short* Anx = As + ((t + 1) & 1) * 16384;
    unsigned short* Bnx = Bs + ((t + 1) & 1) * 16384;
    int k1 = (t + 1) * 64;             // next K-tile elem offset
    bool st = (t < 15);

    // ---- phase 1: quadrant (mh=0, nh=0); stage B q0,q1 of t+1 ----
    {
      bf16x8 a[2][4], b[2][2];
      PHASE_READS(0, 0);
      if (st) {
        stage64(Bg + 0 * 64 * 1024 + k1, Bnx + 0 * 4096, tid);
        stage64(Bg + 1 * 64 * 1024 + k1, Bnx + 1 * 4096, tid);
      }
      BAR();
      PHASE_MFMA(0, 0);
      BAR();
    }
    // ---- phase 2: (0,1); stage B q2,q3; wait so A q1,q3 (this tile) retired ----
    {
      bf16x8 a[2][4], b[2][2];
      PHASE_READS(0, 1);
      if (st) {
        stage64(Bg + 2 * 64 * 1024 + k1, Bnx + 2 * 4096, tid);
        stage64(Bg + 3 * 64 * 1024 + k1, Bnx + 3 * 4096, tid);
      }
      BAR();
      PHASE_MFMA(0, 1);
      if (st) { VMCNT(4); } else { VMCNT(0); }
      BAR();
    }
    // ---- phase 3: (1,0); stage A q0,q2 ----
    {
      bf16x8 a[2][4], b[2][2];
      PHASE_READS(1, 0);
      if (st) {
        stage64(Ag + 0 * 64 * 1024 + k1, Anx + 0 * 4096, tid);
        stage64(Ag + 2 * 64 * 1024 + k1, Anx + 2 * 4096, tid);
      }
      BAR();
      PHASE_MFMA(1, 0);
      BAR();
    }
    // ---- phase 4: (1,1); stage A q1,q3; boundary wait (6 newest may fly) ----
    {
      bf16x8 a[2][4], b[2][2];
      PHASE_READS(1, 1);
      if (st) {
        stage64(Ag + 1 * 64 * 1024 + k1, Anx + 1 * 4096, tid);
        stage64(Ag + 3 * 64 * 1024 + k1, Anx + 3 * 4096, tid);
      }
      BAR();
      PHASE_MFMA(1, 1);
      if (st) { VMCNT(2); }
      BAR();
    }
  }

  // epilogue: C layout col=lane&15, row=(lane>>4)*4+q
#pragma unroll
  for (int mi = 0; mi < 8; ++mi) {
    int mrow = wr * 128 + mi * 16;
    if (mrow >= mLimit) continue;
    int r0 = rowBase + mrow + (lane >> 4) * 4;
#pragma unroll
    for (int ni = 0; ni < 4; ++ni) {
      int col = ny * 256 + wc * 64 + ni * 16 + lane15;
      f32x4 v = acc[mi][ni];
#pragma unroll
      for (int q = 0; q < 4; ++q)
        out[(size_t)(r0 + q) * DFFN_ + col] = v[q];
    }
  }
}

// ---------------- 8. zero tail rows >= total_padded ----------------
__global__ __launch_bounds__(256) void k_ztail(const int* __restrict__ totals,
                                               float* __restrict__ out) {
  int row = TK_ + blockIdx.x;          // 16384 .. 16895
  if (row < totals[0]) return;
  float4 z = {0.f, 0.f, 0.f, 0.f};
  float4* o = (float4*)(out + (size_t)row * DFFN_);
  o[threadIdx.x] = z;
  o[threadIdx.x + 256] = z;
}

extern "C" void kernel_launch(void* const* d_in, const int* in_sizes, int n_in,
                              void* d_out, int out_size, void* d_ws, size_t ws_size,
                              hipStream_t stream) {
  const float* x  = (const float*)d_in[0];
  const float* wr = (const float*)d_in[1];
  const float* w1 = (const float*)d_in[2];
  float* out = (float*)d_out;
  char* ws = (char*)d_ws;

  int* sel     = (int*)(ws + WS_SEL);
  int* counts  = (int*)(ws + WS_COUNTS);
  int* cum_p   = (int*)(ws + WS_CUMP);
  int* totals  = (int*)(ws + WS_TOTALS);
  int* blkCnt  = (int*)(ws + WS_BLKCNT);
  int* blkOff  = (int*)(ws + WS_BLKOFF);
  int* tiles   = (int*)(ws + WS_TILES);
  int* row_src = (int*)(ws + WS_ROWSRC);
  unsigned short* xp  = (unsigned short*)(ws + WS_XPAD);
  unsigned short* w1t = (unsigned short*)(ws + WS_W1T);

  hipMemsetAsync(row_src, 0xFF, CAP_ * sizeof(int), stream);

  k_w1conv<<<dim3(64, 16), 256, 0, stream>>>(w1, w1t);
  k_router<<<T_ / 16, 256, 0, stream>>>(x, wr, sel);
  k_blkcnt<<<NBR_, 256, 0, stream>>>(sel, blkCnt);
  k_scan<<<1, 64, 0, stream>>>(blkCnt, counts, cum_p, totals, blkOff, tiles);
  k_rowsrc<<<NBR_, 256, 0, stream>>>(sel, cum_p, blkOff, row_src);
  k_scatter<<<CAP_, 256, 0, stream>>>(x, row_src, xp);
  k_gemm<<<dim3(MAXT_, 8), 512, 0, stream>>>(xp, w1t, tiles, totals, out);
  k_ztail<<<512, 256, 0, stream>>>(totals, out);
}

// Round 4
// 194.365 us; speedup vs baseline: 2.0206x; 1.0484x over previous
//
#include <hip/hip_runtime.h>
#include <stdint.h>

#define E_       8
#define D_       1024
#define DFFN_    2048
#define T_       8192
#define TK_      16384
#define CAP_     16896
#define NBR_     64        // TK_/256 rank blocks
#define MAXT_    96        // max 256-row tiles

// workspace layout (bytes)
#define WS_SEL      0u          // TK_*4
#define WS_COUNTS   0x10000u    // 8*4
#define WS_CUMP     0x10100u    // 9*4
#define WS_TOTALS   0x10200u    // [0]=total_padded [1]=nTiles
#define WS_BLKCNT   0x10300u    // NBR_*8*4
#define WS_BLKOFF   0x10B00u    // NBR_*8*4
#define WS_TILES    0x11300u    // MAXT_*4
#define WS_ROWSRC   0x12000u    // CAP_*4
#define WS_XPAD     0x23000u    // CAP_*1024*2 = 34603008
#define WS_W1T      (0x23000u + 34603008u)  // 16384*1024*2

typedef __bf16 bf16x8 __attribute__((ext_vector_type(8)));
typedef float  f32x4  __attribute__((ext_vector_type(4)));

#define VMCNT(N) asm volatile("s_waitcnt vmcnt(" #N ")" ::: "memory")
#define BAR()    asm volatile("s_barrier" ::: "memory")

__device__ __forceinline__ unsigned short f2bf(float f) {
  union { float f; uint32_t u; } v; v.f = f;
  return (unsigned short)((v.u + 0x7fffu + ((v.u >> 16) & 1u)) >> 16);
}

// ---------------- 1. router: top-2 expert ids (no global atomics) ----------------
__global__ __launch_bounds__(256) void k_router(const float* __restrict__ x,
                                                const float* __restrict__ wr,
                                                int* __restrict__ sel) {
  __shared__ float lwr[E_ * D_];
  for (int i = threadIdx.x; i < E_ * D_ / 4; i += 256)
    ((float4*)lwr)[i] = ((const float4*)wr)[i];
  __syncthreads();
  int wave = threadIdx.x >> 6, lane = threadIdx.x & 63;

  for (int tk = 0; tk < 4; ++tk) {
    int t = blockIdx.x * 16 + wave * 4 + tk;
    double acc[E_];
#pragma unroll
    for (int e = 0; e < E_; ++e) acc[e] = 0.0;
    const float4* xr = (const float4*)(x + (size_t)t * D_);
#pragma unroll
    for (int j = 0; j < 4; ++j) {
      float4 v = xr[j * 64 + lane];
      int dbase = j * 256 + lane * 4;
#pragma unroll
      for (int e = 0; e < E_; ++e) {
        float4 w = *(const float4*)(lwr + e * D_ + dbase);
        acc[e] += (double)v.x * w.x + (double)v.y * w.y +
                  (double)v.z * w.z + (double)v.w * w.w;
      }
    }
#pragma unroll
    for (int e = 0; e < E_; ++e) {
      acc[e] += __shfl_xor(acc[e], 1, 64);
      acc[e] += __shfl_xor(acc[e], 2, 64);
      acc[e] += __shfl_xor(acc[e], 4, 64);
    }
    double s01 = (lane & 1) ? acc[1] : acc[0];
    double s23 = (lane & 1) ? acc[3] : acc[2];
    double s45 = (lane & 1) ? acc[5] : acc[4];
    double s67 = (lane & 1) ? acc[7] : acc[6];
    double t0 = (lane & 2) ? s23 : s01;
    double t1 = (lane & 2) ? s67 : s45;
    double u  = (lane & 4) ? t1 : t0;
    u += __shfl_xor(u, 8, 64);
    u += __shfl_xor(u, 16, 64);
    u += __shfl_xor(u, 32, 64);
    double lg[E_];
#pragma unroll
    for (int e = 0; e < E_; ++e) lg[e] = __shfl(u, e, 64);
    int e1 = 0; double b1 = lg[0];
#pragma unroll
    for (int e = 1; e < E_; ++e) if (lg[e] > b1) { b1 = lg[e]; e1 = e; }
    int e2 = (e1 == 0) ? 1 : 0; double b2 = lg[e2];
#pragma unroll
    for (int e = 0; e < E_; ++e) if (e != e1 && lg[e] > b2) { b2 = lg[e]; e2 = e; }
    if (lane == 0) {
      sel[2 * t]     = e1;
      sel[2 * t + 1] = e2;
    }
  }
}

// ---------------- 2. per-block expert histograms ----------------
__global__ __launch_bounds__(256) void k_blkcnt(const int* __restrict__ sel,
                                                int* __restrict__ blkCnt) {
  __shared__ int cnt[E_];
  if (threadIdx.x < E_) cnt[threadIdx.x] = 0;
  __syncthreads();
  atomicAdd(&cnt[sel[blockIdx.x * 256 + threadIdx.x]], 1);
  __syncthreads();
  if (threadIdx.x < E_) blkCnt[blockIdx.x * E_ + threadIdx.x] = cnt[threadIdx.x];
}

// ---------------- 3. tiny scans + 256-row tile table (1 block) ----------------
__global__ void k_scan(const int* __restrict__ blkCnt,
                       int* __restrict__ counts,
                       int* __restrict__ cum_p, int* __restrict__ totals,
                       int* __restrict__ blkOff, int* __restrict__ tiles) {
  int tid = threadIdx.x;
  if (tid < E_) {
    int run = 0;
    for (int b = 0; b < NBR_; ++b) {
      blkOff[b * E_ + tid] = run;
      run += blkCnt[b * E_ + tid];
    }
    counts[tid] = run;
  }
  __syncthreads();
  if (tid == 0) {
    int cp = 0, nt = 0;
    cum_p[0] = 0;
    for (int e = 0; e < E_; ++e) {
      int gs = (counts[e] + 63) / 64 * 64;
      int r = 0;
      while (r < gs) {
        int m = (gs - r >= 256) ? 256 : (gs - r);   // 64,128,192,256
        tiles[nt++] = (cp + r) | (e << 20) | (((m >> 6) - 1) << 28);
        r += m;
      }
      cp += gs;
      cum_p[e + 1] = cp;
    }
    totals[0] = cp;
    totals[1] = nt;
  }
}

// ---------------- 4. stable rank -> row_src ----------------
__global__ __launch_bounds__(256) void k_rowsrc(const int* __restrict__ sel,
                                                const int* __restrict__ cum_p,
                                                const int* __restrict__ blkOff,
                                                int* __restrict__ row_src) {
  __shared__ int se[256];
  int i = blockIdx.x * 256 + threadIdx.x;
  int e = sel[i];
  se[threadIdx.x] = e;
  __syncthreads();
  int r = 0;
  for (int j = 0; j < threadIdx.x; ++j) r += (se[j] == e);
  row_src[cum_p[e] + blkOff[blockIdx.x * E_ + e] + r] = i >> 1;
}

// ---------------- 5. scatter x -> padded bf16 rows ----------------
__global__ __launch_bounds__(256) void k_scatter(const float* __restrict__ x,
                                                 const int* __restrict__ row_src,
                                                 unsigned short* __restrict__ xp) {
  int row = blockIdx.x;
  int src = row_src[row];
  ushort4 o;
  if (src >= 0) {
    float4 v = ((const float4*)(x + (size_t)src * D_))[threadIdx.x];
    o.x = f2bf(v.x); o.y = f2bf(v.y); o.z = f2bf(v.z); o.w = f2bf(v.w);
  } else {
    o.x = 0; o.y = 0; o.z = 0; o.w = 0;
  }
  ((ushort4*)(xp + (size_t)row * D_))[threadIdx.x] = o;
}

// ---------------- 6. w1 [d][16384] f32 -> w1t [n][1024] bf16 ----------------
__global__ __launch_bounds__(256) void k_w1conv(const float* __restrict__ w1,
                                                unsigned short* __restrict__ w1t) {
  __shared__ unsigned short lds[64][258];
  int n0 = blockIdx.x * 256, d0 = blockIdx.y * 64;
  int tid = threadIdx.x;
  int rIn = tid >> 6, c4 = tid & 63;
#pragma unroll
  for (int p = 0; p < 16; ++p) {
    int row = p * 4 + rIn;
    float4 v = *(const float4*)(w1 + (size_t)(d0 + row) * 16384 + n0 + c4 * 4);
    lds[row][c4 * 4 + 0] = f2bf(v.x);
    lds[row][c4 * 4 + 1] = f2bf(v.y);
    lds[row][c4 * 4 + 2] = f2bf(v.z);
    lds[row][c4 * 4 + 3] = f2bf(v.w);
  }
  __syncthreads();
  int d2 = (tid & 15) * 4, nn = tid >> 4;
#pragma unroll
  for (int q = 0; q < 16; ++q) {
    int n = q * 16 + nn;
    ushort4 o;
    o.x = lds[d2 + 0][n]; o.y = lds[d2 + 1][n];
    o.z = lds[d2 + 2][n]; o.w = lds[d2 + 3][n];
    *(ushort4*)(w1t + (size_t)(n0 + n) * 1024 + d0 + d2) = o;
  }
}

// ---------------- 7. grouped GEMM: 256x256 tile, BK=64, dedup 4-phase pipeline ----------------
// LDS per buffer: [256 rows][64 bf16] (128B rows), swizzled: byte_in_row ^= (row&7)<<4.
// Staged via global_load_lds (linear dest) from inverse-swizzled global source.

__device__ __forceinline__ void stage64(const unsigned short* gbase, // (row0, k0)
                                        unsigned short* ldsq,        // region base
                                        int tid) {
  int rr = tid >> 3;                                   // row within 64-row region
  int co = ((tid & 7) ^ (rr & 7)) << 3;                // elem offset (inverse swizzle)
  const unsigned short* src = gbase + (size_t)rr * 1024 + co;
  unsigned short* dst = ldsq + ((tid >> 6) << 9);      // wave*512 elems; HW adds lane*16B
  __builtin_amdgcn_global_load_lds(
      (const __attribute__((address_space(1))) void*)src,
      (__attribute__((address_space(3))) void*)dst, 16, 0, 0);
}

#define READ_A(dst, MH, KS)                                                     \
  {                                                                             \
    const unsigned short* p_ = Acur + (wr * 128 + (MH) * 64 + lane15) * 64;     \
    int co_ = (((KS) * 64 + g16) ^ swz) >> 1;                                   \
    _Pragma("unroll") for (int mi = 0; mi < 4; ++mi)                            \
      dst[mi] = *(const bf16x8*)(p_ + mi * 1024 + co_);                         \
  }

#define READ_B(dst, KS)                                                         \
  {                                                                             \
    const unsigned short* p_ = Bcur + (wc * 64 + lane15) * 64;                  \
    int co_ = (((KS) * 64 + g16) ^ swz) >> 1;                                   \
    _Pragma("unroll") for (int ni = 0; ni < 4; ++ni)                            \
      dst[ni] = *(const bf16x8*)(p_ + ni * 1024 + co_);                         \
  }

#define MFMA16(AH, AV, BV)                                                      \
  __builtin_amdgcn_s_setprio(1);                                                \
  _Pragma("unroll") for (int mi = 0; mi < 4; ++mi)                              \
    _Pragma("unroll") for (int ni = 0; ni < 4; ++ni)                            \
      acc[(AH) * 4 + mi][ni] = __builtin_amdgcn_mfma_f32_16x16x32_bf16(         \
          AV[mi], BV[ni], acc[(AH) * 4 + mi][ni], 0, 0, 0);                     \
  __builtin_amdgcn_s_setprio(0);

__global__ __launch_bounds__(512) void k_gemm(const unsigned short* __restrict__ xp,
                                              const unsigned short* __restrict__ w1t,
                                              const int* __restrict__ tiles,
                                              const int* __restrict__ totals,
                                              float* __restrict__ out) {
  // T1: bijective XCD chunking (768 = 8*96); 8 N-tiles of one M-tile share an XCD.
  int P = blockIdx.y * MAXT_ + blockIdx.x;
  int L = (P & 7) * MAXT_ + (P >> 3);
  int mtile = L >> 3, ny = L & 7;
  if (mtile >= totals[1]) return;

  int info = tiles[mtile];
  int rowBase = info & 0xFFFFF;
  int e = (info >> 20) & 0xFF;
  int mLimit = (((info >> 28) & 3) + 1) << 6;

  __shared__ unsigned short As[2 * 256 * 64];
  __shared__ unsigned short Bs[2 * 256 * 64];

  int tid = threadIdx.x, wave = tid >> 6, lane = tid & 63;
  int lane15 = lane & 15;
  int g16 = (lane >> 4) * 16;          // byte offset of k-group
  int swz = (lane15 & 7) << 4;         // read-side swizzle (bytes)
  int wr = wave >> 2, wc = wave & 3;

  const unsigned short* Ag = xp + (size_t)rowBase * D_;
  const unsigned short* Bg = w1t + ((size_t)e * DFFN_ + (size_t)ny * 256) * D_;

  f32x4 acc[8][4];
#pragma unroll
  for (int i = 0; i < 8; ++i)
#pragma unroll
    for (int j = 0; j < 4; ++j) acc[i][j] = (f32x4){0.f, 0.f, 0.f, 0.f};

  // prologue: stage K-tile 0 into buf0 (order: B q0..q3, A q0,q2, A q1,q3)
  stage64(Bg + 0 * 65536, Bs + 0 * 4096, tid);
  stage64(Bg + 1 * 65536, Bs + 1 * 4096, tid);
  stage64(Bg + 2 * 65536, Bs + 2 * 4096, tid);
  stage64(Bg + 3 * 65536, Bs + 3 * 4096, tid);
  stage64(Ag + 0 * 65536, As + 0 * 4096, tid);
  stage64(Ag + 2 * 65536, As + 2 * 4096, tid);
  stage64(Ag + 1 * 65536, As + 1 * 4096, tid);
  stage64(Ag + 3 * 65536, As + 3 * 4096, tid);
  VMCNT(2);
  BAR();

  for (int t = 0; t < 16; ++t) {
    const unsigned short* Acur = As + (t & 1) * 16384;
    const unsigned short* Bcur = Bs + (t & 1) * 16384;
    unsigned short* Anx = As + ((t + 1) & 1) * 16384;
    unsigned short* Bnx = Bs + ((t + 1) & 1) * 16384;
    int k1 = (t + 1) * 64;             // next K-tile elem offset
    bool st = (t < 15);

    bf16x8 a0[4], a1[4], b0[4], b1[4];

    // ---- P1: B[allN, ks0] + A[MH0, ks0]; stage B q0,q1(t+1); retire A q1,q3(t) ----
    READ_B(b0, 0);
    READ_A(a0, 0, 0);
    if (st) {
      stage64(Bg + 0 * 65536 + k1, Bnx + 0 * 4096, tid);
      stage64(Bg + 1 * 65536 + k1, Bnx + 1 * 4096, tid);
    }
    BAR();
    MFMA16(0, a0, b0);
    if (st) { VMCNT(2); } else { VMCNT(0); }
    BAR();

    // ---- P2: A[MH1, ks0] (b0 reused from regs); stage B q2,q3 ----
    READ_A(a1, 1, 0);
    if (st) {
      stage64(Bg + 2 * 65536 + k1, Bnx + 2 * 4096, tid);
      stage64(Bg + 3 * 65536 + k1, Bnx + 3 * 4096, tid);
    }
    BAR();
    MFMA16(1, a1, b0);
    BAR();

    // ---- P3: B[allN, ks1] + A[MH0, ks1]; stage A q0,q2 ----
    READ_B(b1, 1);
    READ_A(a0, 0, 1);
    if (st) {
      stage64(Ag + 0 * 65536 + k1, Anx + 0 * 4096, tid);
      stage64(Ag + 2 * 65536 + k1, Anx + 2 * 4096, tid);
    }
    BAR();
    MFMA16(0, a0, b1);
    BAR();

    // ---- P4: A[MH1, ks1] (b1 reused); stage A q1,q3; boundary wait ----
    READ_A(a1, 1, 1);
    if (st) {
      stage64(Ag + 1 * 65536 + k1, Anx + 1 * 4096, tid);
      stage64(Ag + 3 * 65536 + k1, Anx + 3 * 4096, tid);
    }
    BAR();
    MFMA16(1, a1, b1);
    if (st) { VMCNT(2); }
    BAR();
  }

  // epilogue: C layout col=lane&15, row=(lane>>4)*4+q
#pragma unroll
  for (int mi = 0; mi < 8; ++mi) {
    int mrow = wr * 128 + mi * 16;
    if (mrow >= mLimit) continue;
    int r0 = rowBase + mrow + (lane >> 4) * 4;
#pragma unroll
    for (int ni = 0; ni < 4; ++ni) {
      int col = ny * 256 + wc * 64 + ni * 16 + lane15;
      f32x4 v = acc[mi][ni];
#pragma unroll
      for (int q = 0; q < 4; ++q)
        out[(size_t)(r0 + q) * DFFN_ + col] = v[q];
    }
  }
}

// ---------------- 8. zero tail rows >= total_padded ----------------
__global__ __launch_bounds__(256) void k_ztail(const int* __restrict__ totals,
                                               float* __restrict__ out) {
  int row = TK_ + blockIdx.x;          // 16384 .. 16895
  if (row < totals[0]) return;
  float4 z = {0.f, 0.f, 0.f, 0.f};
  float4* o = (float4*)(out + (size_t)row * DFFN_);
  o[threadIdx.x] = z;
  o[threadIdx.x + 256] = z;
}

extern "C" void kernel_launch(void* const* d_in, const int* in_sizes, int n_in,
                              void* d_out, int out_size, void* d_ws, size_t ws_size,
                              hipStream_t stream) {
  const float* x  = (const float*)d_in[0];
  const float* wr = (const float*)d_in[1];
  const float* w1 = (const float*)d_in[2];
  float* out = (float*)d_out;
  char* ws = (char*)d_ws;

  int* sel     = (int*)(ws + WS_SEL);
  int* counts  = (int*)(ws + WS_COUNTS);
  int* cum_p   = (int*)(ws + WS_CUMP);
  int* totals  = (int*)(ws + WS_TOTALS);
  int* blkCnt  = (int*)(ws + WS_BLKCNT);
  int* blkOff  = (int*)(ws + WS_BLKOFF);
  int* tiles   = (int*)(ws + WS_TILES);
  int* row_src = (int*)(ws + WS_ROWSRC);
  unsigned short* xp  = (unsigned short*)(ws + WS_XPAD);
  unsigned short* w1t = (unsigned short*)(ws + WS_W1T);

  hipMemsetAsync(row_src, 0xFF, CAP_ * sizeof(int), stream);

  k_w1conv<<<dim3(64, 16), 256, 0, stream>>>(w1, w1t);
  k_router<<<T_ / 16, 256, 0, stream>>>(x, wr, sel);
  k_blkcnt<<<NBR_, 256, 0, stream>>>(sel, blkCnt);
  k_scan<<<1, 64, 0, stream>>>(blkCnt, counts, cum_p, totals, blkOff, tiles);
  k_rowsrc<<<NBR_, 256, 0, stream>>>(sel, cum_p, blkOff, row_src);
  k_scatter<<<CAP_, 256, 0, stream>>>(x, row_src, xp);
  k_gemm<<<dim3(MAXT_, 8), 512, 0, stream>>>(xp, w1t, tiles, totals, out);
  k_ztail<<<512, 256, 0, stream>>>(totals, out);
}

// Round 5
// 189.317 us; speedup vs baseline: 2.0745x; 1.0267x over previous
//
#include <hip/hip_runtime.h>
#include <stdint.h>

#define E_       8
#define D_       1024
#define DFFN_    2048
#define T_       8192
#define TK_      16384
#define CAP_     16896
#define NBR_     64        // TK_/256 rank blocks
#define MAXT_    96        // max 256-row tiles

// workspace layout (bytes)
#define WS_SEL      0u          // TK_*4
#define WS_COUNTS   0x10000u    // 8*4
#define WS_CUMP     0x10100u    // 9*4
#define WS_TOTALS   0x10200u    // [0]=total_padded [1]=nTiles
#define WS_BLKCNT   0x10300u    // NBR_*8*4
#define WS_BLKOFF   0x10B00u    // NBR_*8*4
#define WS_TILES    0x11300u    // MAXT_*4
#define WS_ROWSRC   0x12000u    // CAP_*4
#define WS_XPAD     0x23000u    // CAP_*1024*2 = 34603008
#define WS_W1T      (0x23000u + 34603008u)  // 16384*1024*2

typedef __bf16 bf16x8 __attribute__((ext_vector_type(8)));
typedef float  f32x4  __attribute__((ext_vector_type(4)));

#define VMCNT(N) asm volatile("s_waitcnt vmcnt(" #N ")" ::: "memory")
#define BAR()    asm volatile("s_barrier" ::: "memory")

__device__ __forceinline__ unsigned short f2bf(float f) {
  union { float f; uint32_t u; } v; v.f = f;
  return (unsigned short)((v.u + 0x7fffu + ((v.u >> 16) & 1u)) >> 16);
}

// ---------------- 1. router: top-2 expert ids (no global atomics) ----------------
__global__ __launch_bounds__(256) void k_router(const float* __restrict__ x,
                                                const float* __restrict__ wr,
                                                int* __restrict__ sel) {
  __shared__ float lwr[E_ * D_];
  for (int i = threadIdx.x; i < E_ * D_ / 4; i += 256)
    ((float4*)lwr)[i] = ((const float4*)wr)[i];
  __syncthreads();
  int wave = threadIdx.x >> 6, lane = threadIdx.x & 63;

  for (int tk = 0; tk < 4; ++tk) {
    int t = blockIdx.x * 16 + wave * 4 + tk;
    double acc[E_];
#pragma unroll
    for (int e = 0; e < E_; ++e) acc[e] = 0.0;
    const float4* xr = (const float4*)(x + (size_t)t * D_);
#pragma unroll
    for (int j = 0; j < 4; ++j) {
      float4 v = xr[j * 64 + lane];
      int dbase = j * 256 + lane * 4;
#pragma unroll
      for (int e = 0; e < E_; ++e) {
        float4 w = *(const float4*)(lwr + e * D_ + dbase);
        acc[e] += (double)v.x * w.x + (double)v.y * w.y +
                  (double)v.z * w.z + (double)v.w * w.w;
      }
    }
#pragma unroll
    for (int e = 0; e < E_; ++e) {
      acc[e] += __shfl_xor(acc[e], 1, 64);
      acc[e] += __shfl_xor(acc[e], 2, 64);
      acc[e] += __shfl_xor(acc[e], 4, 64);
    }
    double s01 = (lane & 1) ? acc[1] : acc[0];
    double s23 = (lane & 1) ? acc[3] : acc[2];
    double s45 = (lane & 1) ? acc[5] : acc[4];
    double s67 = (lane & 1) ? acc[7] : acc[6];
    double t0 = (lane & 2) ? s23 : s01;
    double t1 = (lane & 2) ? s67 : s45;
    double u  = (lane & 4) ? t1 : t0;
    u += __shfl_xor(u, 8, 64);
    u += __shfl_xor(u, 16, 64);
    u += __shfl_xor(u, 32, 64);
    double lg[E_];
#pragma unroll
    for (int e = 0; e < E_; ++e) lg[e] = __shfl(u, e, 64);
    int e1 = 0; double b1 = lg[0];
#pragma unroll
    for (int e = 1; e < E_; ++e) if (lg[e] > b1) { b1 = lg[e]; e1 = e; }
    int e2 = (e1 == 0) ? 1 : 0; double b2 = lg[e2];
#pragma unroll
    for (int e = 0; e < E_; ++e) if (e != e1 && lg[e] > b2) { b2 = lg[e]; e2 = e; }
    if (lane == 0) {
      sel[2 * t]     = e1;
      sel[2 * t + 1] = e2;
    }
  }
}

// ---------------- 2. per-block expert histograms ----------------
__global__ __launch_bounds__(256) void k_blkcnt(const int* __restrict__ sel,
                                                int* __restrict__ blkCnt) {
  __shared__ int cnt[E_];
  if (threadIdx.x < E_) cnt[threadIdx.x] = 0;
  __syncthreads();
  atomicAdd(&cnt[sel[blockIdx.x * 256 + threadIdx.x]], 1);
  __syncthreads();
  if (threadIdx.x < E_) blkCnt[blockIdx.x * E_ + threadIdx.x] = cnt[threadIdx.x];
}

// ---------------- 3. tiny scans + 256-row tile table (1 block) ----------------
__global__ void k_scan(const int* __restrict__ blkCnt,
                       int* __restrict__ counts,
                       int* __restrict__ cum_p, int* __restrict__ totals,
                       int* __restrict__ blkOff, int* __restrict__ tiles) {
  int tid = threadIdx.x;
  if (tid < E_) {
    int run = 0;
    for (int b = 0; b < NBR_; ++b) {
      blkOff[b * E_ + tid] = run;
      run += blkCnt[b * E_ + tid];
    }
    counts[tid] = run;
  }
  __syncthreads();
  if (tid == 0) {
    int cp = 0, nt = 0;
    cum_p[0] = 0;
    for (int e = 0; e < E_; ++e) {
      int gs = (counts[e] + 63) / 64 * 64;
      int r = 0;
      while (r < gs) {
        int m = (gs - r >= 256) ? 256 : (gs - r);   // 64,128,192,256
        tiles[nt++] = (cp + r) | (e << 20) | (((m >> 6) - 1) << 28);
        r += m;
      }
      cp += gs;
      cum_p[e + 1] = cp;
    }
    totals[0] = cp;
    totals[1] = nt;
  }
}

// ---------------- 4. stable rank -> row_src ----------------
__global__ __launch_bounds__(256) void k_rowsrc(const int* __restrict__ sel,
                                                const int* __restrict__ cum_p,
                                                const int* __restrict__ blkOff,
                                                int* __restrict__ row_src) {
  __shared__ int se[256];
  int i = blockIdx.x * 256 + threadIdx.x;
  int e = sel[i];
  se[threadIdx.x] = e;
  __syncthreads();
  int r = 0;
  for (int j = 0; j < threadIdx.x; ++j) r += (se[j] == e);
  row_src[cum_p[e] + blkOff[blockIdx.x * E_ + e] + r] = i >> 1;
}

// ---------------- 5. scatter x -> padded bf16 rows ----------------
__global__ __launch_bounds__(256) void k_scatter(const float* __restrict__ x,
                                                 const int* __restrict__ row_src,
                                                 unsigned short* __restrict__ xp) {
  int row = blockIdx.x;
  int src = row_src[row];
  ushort4 o;
  if (src >= 0) {
    float4 v = ((const float4*)(x + (size_t)src * D_))[threadIdx.x];
    o.x = f2bf(v.x); o.y = f2bf(v.y); o.z = f2bf(v.z); o.w = f2bf(v.w);
  } else {
    o.x = 0; o.y = 0; o.z = 0; o.w = 0;
  }
  ((ushort4*)(xp + (size_t)row * D_))[threadIdx.x] = o;
}

// ---------------- 6. w1 [d][16384] f32 -> w1t [n][1024] bf16 ----------------
__global__ __launch_bounds__(256) void k_w1conv(const float* __restrict__ w1,
                                                unsigned short* __restrict__ w1t) {
  __shared__ unsigned short lds[64][258];
  int n0 = blockIdx.x * 256, d0 = blockIdx.y * 64;
  int tid = threadIdx.x;
  int rIn = tid >> 6, c4 = tid & 63;
#pragma unroll
  for (int p = 0; p < 16; ++p) {
    int row = p * 4 + rIn;
    float4 v = *(const float4*)(w1 + (size_t)(d0 + row) * 16384 + n0 + c4 * 4);
    lds[row][c4 * 4 + 0] = f2bf(v.x);
    lds[row][c4 * 4 + 1] = f2bf(v.y);
    lds[row][c4 * 4 + 2] = f2bf(v.z);
    lds[row][c4 * 4 + 3] = f2bf(v.w);
  }
  __syncthreads();
  int d2 = (tid & 15) * 4, nn = tid >> 4;
#pragma unroll
  for (int q = 0; q < 16; ++q) {
    int n = q * 16 + nn;
    ushort4 o;
    o.x = lds[d2 + 0][n]; o.y = lds[d2 + 1][n];
    o.z = lds[d2 + 2][n]; o.w = lds[d2 + 3][n];
    *(ushort4*)(w1t + (size_t)(n0 + n) * 1024 + d0 + d2) = o;
  }
}

// ---------------- 7. grouped GEMM: 256x256, BK=64, dbuf, ONE barrier per K-tile ----------------
// LDS per buffer: [256 rows][64 bf16] (128B rows), swizzled: byte_in_row ^= (row&7)<<4.
// dbuf => no intra-tile hazards: stages write buf(t+1) while all reads hit buf(t).
// Sync = single {VMCNT(0); s_barrier} at each K-tile boundary. Compiler free-schedules
// the 24 ds_reads + 64 MFMA + 8 stage-issues within the tile (counted lgkmcnt overlap).

__device__ __forceinline__ void stage64(const unsigned short* gbase, // (row0, k0)
                                        unsigned short* ldsq,        // region base
                                        int tid) {
  int rr = tid >> 3;                                   // row within 64-row region
  int co = ((tid & 7) ^ (rr & 7)) << 3;                // elem offset (inverse swizzle)
  const unsigned short* src = gbase + (size_t)rr * 1024 + co;
  unsigned short* dst = ldsq + ((tid >> 6) << 9);      // wave*512 elems; HW adds lane*16B
  __builtin_amdgcn_global_load_lds(
      (const __attribute__((address_space(1))) void*)src,
      (__attribute__((address_space(3))) void*)dst, 16, 0, 0);
}

#define READ_A(dst, MH, KS)                                                     \
  {                                                                             \
    const unsigned short* p_ = Acur + (wr * 128 + (MH) * 64 + lane15) * 64;     \
    int co_ = (((KS) * 64 + g16) ^ swz) >> 1;                                   \
    _Pragma("unroll") for (int mi = 0; mi < 4; ++mi)                            \
      dst[mi] = *(const bf16x8*)(p_ + mi * 1024 + co_);                         \
  }

#define READ_B(dst, KS)                                                         \
  {                                                                             \
    const unsigned short* p_ = Bcur + (wc * 64 + lane15) * 64;                  \
    int co_ = (((KS) * 64 + g16) ^ swz) >> 1;                                   \
    _Pragma("unroll") for (int ni = 0; ni < 4; ++ni)                            \
      dst[ni] = *(const bf16x8*)(p_ + ni * 1024 + co_);                         \
  }

#define MFMA32(A0, A1, BV)                                                      \
  __builtin_amdgcn_s_setprio(1);                                                \
  _Pragma("unroll") for (int mi = 0; mi < 4; ++mi)                              \
    _Pragma("unroll") for (int ni = 0; ni < 4; ++ni)                            \
      acc[mi][ni] = __builtin_amdgcn_mfma_f32_16x16x32_bf16(                    \
          A0[mi], BV[ni], acc[mi][ni], 0, 0, 0);                                \
  _Pragma("unroll") for (int mi = 0; mi < 4; ++mi)                              \
    _Pragma("unroll") for (int ni = 0; ni < 4; ++ni)                            \
      acc[4 + mi][ni] = __builtin_amdgcn_mfma_f32_16x16x32_bf16(                \
          A1[mi], BV[ni], acc[4 + mi][ni], 0, 0, 0);                            \
  __builtin_amdgcn_s_setprio(0);

__global__ __launch_bounds__(512) void k_gemm(const unsigned short* __restrict__ xp,
                                              const unsigned short* __restrict__ w1t,
                                              const int* __restrict__ tiles,
                                              const int* __restrict__ totals,
                                              float* __restrict__ out) {
  // T1: bijective XCD chunking (768 = 8*96); 8 N-tiles of one M-tile share an XCD.
  int P = blockIdx.y * MAXT_ + blockIdx.x;
  int L = (P & 7) * MAXT_ + (P >> 3);
  int mtile = L >> 3, ny = L & 7;
  if (mtile >= totals[1]) return;

  int info = tiles[mtile];
  int rowBase = info & 0xFFFFF;
  int e = (info >> 20) & 0xFF;
  int mLimit = (((info >> 28) & 3) + 1) << 6;

  __shared__ unsigned short As[2 * 256 * 64];
  __shared__ unsigned short Bs[2 * 256 * 64];

  int tid = threadIdx.x, wave = tid >> 6, lane = tid & 63;
  int lane15 = lane & 15;
  int g16 = (lane >> 4) * 16;          // byte offset of k-group
  int swz = (lane15 & 7) << 4;         // read-side swizzle (bytes)
  int wr = wave >> 2, wc = wave & 3;

  const unsigned short* Ag = xp + (size_t)rowBase * D_;
  const unsigned short* Bg = w1t + ((size_t)e * DFFN_ + (size_t)ny * 256) * D_;

  f32x4 acc[8][4];
#pragma unroll
  for (int i = 0; i < 8; ++i)
#pragma unroll
    for (int j = 0; j < 4; ++j) acc[i][j] = (f32x4){0.f, 0.f, 0.f, 0.f};

  // prologue: stage K-tile 0 into buf0 (A first: L3-latency; B last: L2-fast)
  stage64(Ag + 0 * 65536, As + 0 * 4096, tid);
  stage64(Ag + 1 * 65536, As + 1 * 4096, tid);
  stage64(Ag + 2 * 65536, As + 2 * 4096, tid);
  stage64(Ag + 3 * 65536, As + 3 * 4096, tid);
  stage64(Bg + 0 * 65536, Bs + 0 * 4096, tid);
  stage64(Bg + 1 * 65536, Bs + 1 * 4096, tid);
  stage64(Bg + 2 * 65536, Bs + 2 * 4096, tid);
  stage64(Bg + 3 * 65536, Bs + 3 * 4096, tid);
  VMCNT(0);
  BAR();

  for (int t = 0; t < 16; ++t) {
    const unsigned short* Acur = As + (t & 1) * 16384;
    const unsigned short* Bcur = Bs + (t & 1) * 16384;
    unsigned short* Anx = As + ((t + 1) & 1) * 16384;
    unsigned short* Bnx = Bs + ((t + 1) & 1) * 16384;
    int k1 = (t + 1) * 64;             // next K-tile elem offset
    bool st = (t < 15);

    bf16x8 a0[4], a1[4], b0[4], b1[4];

    // ---- ks0 half: reads + stage A(t+1) + 32 MFMA (no barrier) ----
    READ_B(b0, 0);
    READ_A(a0, 0, 0);
    READ_A(a1, 1, 0);
    if (st) {
      stage64(Ag + 0 * 65536 + k1, Anx + 0 * 4096, tid);
      stage64(Ag + 1 * 65536 + k1, Anx + 1 * 4096, tid);
      stage64(Ag + 2 * 65536 + k1, Anx + 2 * 4096, tid);
      stage64(Ag + 3 * 65536 + k1, Anx + 3 * 4096, tid);
    }
    MFMA32(a0, a1, b0);

    // ---- ks1 half: reads + stage B(t+1) + 32 MFMA ----
    READ_B(b1, 1);
    READ_A(a0, 0, 1);
    READ_A(a1, 1, 1);
    if (st) {
      stage64(Bg + 0 * 65536 + k1, Bnx + 0 * 4096, tid);
      stage64(Bg + 1 * 65536 + k1, Bnx + 1 * 4096, tid);
      stage64(Bg + 2 * 65536 + k1, Bnx + 2 * 4096, tid);
      stage64(Bg + 3 * 65536 + k1, Bnx + 3 * 4096, tid);
    }
    MFMA32(a0, a1, b1);

    // ---- single K-tile boundary sync: all 8 stages of t+1 retired, then swap ----
    VMCNT(0);
    BAR();
  }

  // epilogue: C layout col=lane&15, row=(lane>>4)*4+q
#pragma unroll
  for (int mi = 0; mi < 8; ++mi) {
    int mrow = wr * 128 + mi * 16;
    if (mrow >= mLimit) continue;
    int r0 = rowBase + mrow + (lane >> 4) * 4;
#pragma unroll
    for (int ni = 0; ni < 4; ++ni) {
      int col = ny * 256 + wc * 64 + ni * 16 + lane15;
      f32x4 v = acc[mi][ni];
#pragma unroll
      for (int q = 0; q < 4; ++q)
        out[(size_t)(r0 + q) * DFFN_ + col] = v[q];
    }
  }
}

// ---------------- 8. zero tail rows >= total_padded ----------------
__global__ __launch_bounds__(256) void k_ztail(const int* __restrict__ totals,
                                               float* __restrict__ out) {
  int row = TK_ + blockIdx.x;          // 16384 .. 16895
  if (row < totals[0]) return;
  float4 z = {0.f, 0.f, 0.f, 0.f};
  float4* o = (float4*)(out + (size_t)row * DFFN_);
  o[threadIdx.x] = z;
  o[threadIdx.x + 256] = z;
}

extern "C" void kernel_launch(void* const* d_in, const int* in_sizes, int n_in,
                              void* d_out, int out_size, void* d_ws, size_t ws_size,
                              hipStream_t stream) {
  const float* x  = (const float*)d_in[0];
  const float* wr = (const float*)d_in[1];
  const float* w1 = (const float*)d_in[2];
  float* out = (float*)d_out;
  char* ws = (char*)d_ws;

  int* sel     = (int*)(ws + WS_SEL);
  int* counts  = (int*)(ws + WS_COUNTS);
  int* cum_p   = (int*)(ws + WS_CUMP);
  int* totals  = (int*)(ws + WS_TOTALS);
  int* blkCnt  = (int*)(ws + WS_BLKCNT);
  int* blkOff  = (int*)(ws + WS_BLKOFF);
  int* tiles   = (int*)(ws + WS_TILES);
  int* row_src = (int*)(ws + WS_ROWSRC);
  unsigned short* xp  = (unsigned short*)(ws + WS_XPAD);
  unsigned short* w1t = (unsigned short*)(ws + WS_W1T);

  hipMemsetAsync(row_src, 0xFF, CAP_ * sizeof(int), stream);

  k_w1conv<<<dim3(64, 16), 256, 0, stream>>>(w1, w1t);
  k_router<<<T_ / 16, 256, 0, stream>>>(x, wr, sel);
  k_blkcnt<<<NBR_, 256, 0, stream>>>(sel, blkCnt);
  k_scan<<<1, 64, 0, stream>>>(blkCnt, counts, cum_p, totals, blkOff, tiles);
  k_rowsrc<<<NBR_, 256, 0, stream>>>(sel, cum_p, blkOff, row_src);
  k_scatter<<<CAP_, 256, 0, stream>>>(x, row_src, xp);
  k_gemm<<<dim3(MAXT_, 8), 512, 0, stream>>>(xp, w1t, tiles, totals, out);
  k_ztail<<<512, 256, 0, stream>>>(totals, out);
}